// Round 1
// baseline (571.209 us; speedup 1.0000x reference)
//
#include <hip/hip_runtime.h>

// Problem geometry (fixed by the reference)
#define BATCH 2
#define C 512
#define C2 256
#define V 4096          // D*W*H = 16*16*16
#define EPS 1e-5f
#define SLOPE 0.01f

__device__ __forceinline__ float leaky(float x) {
    return x >= 0.f ? x : SLOPE * x;
}

// neighbor voxel index for shift k (0:d-1, 1:d+1, 2:w-1, 3:w+1, 4:h-1, 5:h+1), cyclic
__device__ __forceinline__ int nbr(int v, int k) {
    int h = v & 15, w = (v >> 4) & 15, d = v >> 8;
    switch (k) {
        case 0: return (v & 0x0FF) | (((d + 15) & 15) << 8);
        case 1: return (v & 0x0FF) | (((d + 1) & 15) << 8);
        case 2: return (v & 0xF0F) | (((w + 15) & 15) << 4);
        case 3: return (v & 0xF0F) | (((w + 1) & 15) << 4);
        case 4: return (v & 0xFF0) | ((h + 15) & 15);
        default: return (v & 0xFF0) | ((h + 1) & 15);
    }
}

// ---------------------------------------------------------------------------
// Kernel A: agg[b,c,v] = leaky(bn_s(b_ea + sum_k w_ea[k]*(x_nb*x + topo[v,k])))
// ---------------------------------------------------------------------------
__global__ __launch_bounds__(256) void k_agg(
    const float* __restrict__ x, const float* __restrict__ topo,
    const float* __restrict__ w_ea, const float* __restrict__ b_ea,
    const float* __restrict__ g_ea, const float* __restrict__ be_ea,
    const float* __restrict__ rm_ea, const float* __restrict__ rv_ea,
    float* __restrict__ agg)
{
    int i = blockIdx.x * 256 + threadIdx.x;     // over BATCH*C*V
    if (i >= BATCH * C * V) return;
    int v = i & (V - 1);
    int base = i - v;                           // start of this (b,c) row
    int h = v & 15, w = (v >> 4) & 15, d = v >> 8;
    int v0 = (v & 0x0FF) | (((d + 15) & 15) << 8);
    int v1 = (v & 0x0FF) | (((d + 1) & 15) << 8);
    int v2 = (v & 0xF0F) | (((w + 15) & 15) << 4);
    int v3 = (v & 0xF0F) | (((w + 1) & 15) << 4);
    int v4 = (v & 0xFF0) | ((h + 15) & 15);
    int v5 = (v & 0xFF0) | ((h + 1) & 15);
    float xv = x[i];
    const float* tp = topo + (size_t)v * 6;
    float s = b_ea[0];
    s = fmaf(w_ea[0], fmaf(x[base + v0], xv, tp[0]), s);
    s = fmaf(w_ea[1], fmaf(x[base + v1], xv, tp[1]), s);
    s = fmaf(w_ea[2], fmaf(x[base + v2], xv, tp[2]), s);
    s = fmaf(w_ea[3], fmaf(x[base + v3], xv, tp[3]), s);
    s = fmaf(w_ea[4], fmaf(x[base + v4], xv, tp[4]), s);
    s = fmaf(w_ea[5], fmaf(x[base + v5], xv, tp[5]), s);
    float sc = rsqrtf(rv_ea[0] + EPS) * g_ea[0];
    float a = (s - rm_ea[0]) * sc + be_ea[0];
    agg[i] = leaky(a);
}

// ---------------------------------------------------------------------------
// Kernel B: uv[b,o,v] = leaky(bn_c(sum_c w_v[o,c]*x + sum_c w_v[o,512+c]*agg + b_v))
// GEMM: M=256 (o), K=1024 ([x;agg]), N=V per batch. Tile 64x64, block 256.
// ---------------------------------------------------------------------------
__global__ __launch_bounds__(256) void k_uv(
    const float* __restrict__ x, const float* __restrict__ agg,
    const float* __restrict__ w_v, const float* __restrict__ b_v,
    const float* __restrict__ g_v, const float* __restrict__ be_v,
    const float* __restrict__ rm_v, const float* __restrict__ rv_v,
    float* __restrict__ uvout)
{
    const int b  = blockIdx.z;
    const int vt = blockIdx.x * 64;
    const int ot = blockIdx.y * 64;
    const int tid = threadIdx.x;
    const int tx = tid & 15, ty = tid >> 4;
    const float* xb = x + (size_t)b * C * V;
    const float* ab = agg + (size_t)b * C * V;

    __shared__ float Wt[16][68];   // [c][o], padded
    __shared__ float Bt[16][64];   // [c][v]

    float acc[4][4] = {};

    for (int k0 = 0; k0 < 2 * C; k0 += 16) {
        const float* src = (k0 < C) ? xb : ab;
        const int row = k0 & (C - 1);
        // stage W tile: 64 o x 16 c
        #pragma unroll
        for (int r = 0; r < 4; ++r) {
            int o = (tid >> 4) + r * 16;
            int c = tid & 15;
            Wt[c][o] = w_v[(size_t)(ot + o) * (2 * C) + k0 + c];
        }
        // stage B tile: 16 c x 64 v
        #pragma unroll
        for (int r = 0; r < 4; ++r) {
            int c = (tid >> 6) + r * 4;
            int vv = tid & 63;
            Bt[c][vv] = src[(size_t)(row + c) * V + vt + vv];
        }
        __syncthreads();
        #pragma unroll
        for (int c = 0; c < 16; ++c) {
            const float4 wv = *(const float4*)(&Wt[c][ty * 4]);
            const float4 bv = *(const float4*)(&Bt[c][tx * 4]);
            const float wa[4] = {wv.x, wv.y, wv.z, wv.w};
            const float ba[4] = {bv.x, bv.y, bv.z, bv.w};
            #pragma unroll
            for (int oi = 0; oi < 4; ++oi)
                #pragma unroll
                for (int vi = 0; vi < 4; ++vi)
                    acc[oi][vi] = fmaf(wa[oi], ba[vi], acc[oi][vi]);
        }
        __syncthreads();
    }

    #pragma unroll
    for (int oi = 0; oi < 4; ++oi) {
        int o = ot + ty * 4 + oi;
        float sc  = rsqrtf(rv_v[o] + EPS) * g_v[o];
        float off = b_v[o] - rm_v[o];
        float4 outv;
        float t;
        t = (acc[oi][0] + off) * sc + be_v[o]; outv.x = leaky(t);
        t = (acc[oi][1] + off) * sc + be_v[o]; outv.y = leaky(t);
        t = (acc[oi][2] + off) * sc + be_v[o]; outv.z = leaky(t);
        t = (acc[oi][3] + off) * sc + be_v[o]; outv.w = leaky(t);
        *(float4*)(&uvout[((size_t)b * C2 + o) * V + vt + tx * 4]) = outv;
    }
}

// ---------------------------------------------------------------------------
// Kernel C: upd[b,o,v] = uv * leaky(bn_s(sum_k w_r[k]*ue_k + b_r))
//   ue_k = leaky(bn_c(sxe + se_k + b_e)),  sxe = W_e[:, :512] @ x,
//   se_k = W_e[:, 512:] @ (x_nb_k * x + topo_k)
// 7 GEMM phases (K=512 each) fused into one kernel; ur reduced in registers.
// ---------------------------------------------------------------------------
__global__ __launch_bounds__(256) void k_upd(
    const float* __restrict__ x, const float* __restrict__ topo,
    const float* __restrict__ w_e, const float* __restrict__ b_e,
    const float* __restrict__ g_e, const float* __restrict__ be_e,
    const float* __restrict__ rm_e, const float* __restrict__ rv_e,
    const float* __restrict__ w_r, const float* __restrict__ b_r,
    const float* __restrict__ g_r, const float* __restrict__ be_r,
    const float* __restrict__ rm_r, const float* __restrict__ rv_r,
    const float* __restrict__ uvin, float* __restrict__ upd)
{
    const int b  = blockIdx.z;
    const int vt = blockIdx.x * 64;
    const int ot = blockIdx.y * 64;
    const int tid = threadIdx.x;
    const int tx = tid & 15, ty = tid >> 4;
    const float* xb = x + (size_t)b * C * V;

    __shared__ float Wt[16][68];
    __shared__ float Bt[16][64];

    float sxe[4][4] = {};
    float ur[4][4]  = {};

    // ---- phase 0: sxe = W_e[:, :512] @ x ----
    for (int k0 = 0; k0 < C; k0 += 16) {
        #pragma unroll
        for (int r = 0; r < 4; ++r) {
            int o = (tid >> 4) + r * 16;
            int c = tid & 15;
            Wt[c][o] = w_e[(size_t)(ot + o) * (2 * C) + k0 + c];
        }
        #pragma unroll
        for (int r = 0; r < 4; ++r) {
            int c = (tid >> 6) + r * 4;
            int vv = tid & 63;
            Bt[c][vv] = xb[(size_t)(k0 + c) * V + vt + vv];
        }
        __syncthreads();
        #pragma unroll
        for (int c = 0; c < 16; ++c) {
            const float4 wv = *(const float4*)(&Wt[c][ty * 4]);
            const float4 bv = *(const float4*)(&Bt[c][tx * 4]);
            const float wa[4] = {wv.x, wv.y, wv.z, wv.w};
            const float ba[4] = {bv.x, bv.y, bv.z, bv.w};
            #pragma unroll
            for (int oi = 0; oi < 4; ++oi)
                #pragma unroll
                for (int vi = 0; vi < 4; ++vi)
                    sxe[oi][vi] = fmaf(wa[oi], ba[vi], sxe[oi][vi]);
        }
        __syncthreads();
    }

    // per-thread BN_e constants for its 4 output channels
    float sce[4], bee[4], bmr[4];
    #pragma unroll
    for (int oi = 0; oi < 4; ++oi) {
        int o = ot + ty * 4 + oi;
        sce[oi] = rsqrtf(rv_e[o] + EPS) * g_e[o];
        bee[oi] = be_e[o];
        bmr[oi] = b_e[o] - rm_e[o];
    }

    // ---- phases k=0..5: se_k GEMM + activation + ur accumulation ----
    #pragma unroll 1
    for (int k = 0; k < 6; ++k) {
        const int sv  = vt + (tid & 63);        // voxel this thread stages
        const int nb  = nbr(sv, k);
        const float tpv = topo[(size_t)sv * 6 + k];
        float acc[4][4] = {};
        for (int k0 = 0; k0 < C; k0 += 16) {
            #pragma unroll
            for (int r = 0; r < 4; ++r) {
                int o = (tid >> 4) + r * 16;
                int c = tid & 15;
                Wt[c][o] = w_e[(size_t)(ot + o) * (2 * C) + C + k0 + c];
            }
            #pragma unroll
            for (int r = 0; r < 4; ++r) {
                int c = (tid >> 6) + r * 4;
                float xa = xb[(size_t)(k0 + c) * V + sv];
                float xn = xb[(size_t)(k0 + c) * V + nb];
                Bt[c][tid & 63] = fmaf(xa, xn, tpv);
            }
            __syncthreads();
            #pragma unroll
            for (int c = 0; c < 16; ++c) {
                const float4 wv = *(const float4*)(&Wt[c][ty * 4]);
                const float4 bv = *(const float4*)(&Bt[c][tx * 4]);
                const float wa[4] = {wv.x, wv.y, wv.z, wv.w};
                const float ba[4] = {bv.x, bv.y, bv.z, bv.w};
                #pragma unroll
                for (int oi = 0; oi < 4; ++oi)
                    #pragma unroll
                    for (int vi = 0; vi < 4; ++vi)
                        acc[oi][vi] = fmaf(wa[oi], ba[vi], acc[oi][vi]);
            }
            __syncthreads();
        }
        const float wr = w_r[k];
        #pragma unroll
        for (int oi = 0; oi < 4; ++oi)
            #pragma unroll
            for (int vi = 0; vi < 4; ++vi) {
                float ue = (sxe[oi][vi] + acc[oi][vi] + bmr[oi]) * sce[oi] + bee[oi];
                ur[oi][vi] = fmaf(wr, leaky(ue), ur[oi][vi]);
            }
    }

    // ---- epilogue: ur -> bn_s -> leaky; upd = uv * ur ----
    const float scr = rsqrtf(rv_r[0] + EPS) * g_r[0];
    const float offr = b_r[0] - rm_r[0];
    const float ber = be_r[0];
    #pragma unroll
    for (int oi = 0; oi < 4; ++oi) {
        int o = ot + ty * 4 + oi;
        size_t idx = ((size_t)b * C2 + o) * V + vt + tx * 4;
        float4 uvv = *(const float4*)(&uvin[idx]);
        float4 outv;
        float t;
        t = (ur[oi][0] + offr) * scr + ber; outv.x = uvv.x * leaky(t);
        t = (ur[oi][1] + offr) * scr + ber; outv.y = uvv.y * leaky(t);
        t = (ur[oi][2] + offr) * scr + ber; outv.z = uvv.z * leaky(t);
        t = (ur[oi][3] + offr) * scr + ber; outv.w = uvv.w * leaky(t);
        *(float4*)(&upd[idx]) = outv;
    }
}

// ---------------------------------------------------------------------------
// Kernel D: out[b,o2,v] = leaky(bn_c(W_f[:, :512] @ x + W_f[:, 512:768] @ upd))
// GEMM: M=512, K=768, N=V per batch.
// ---------------------------------------------------------------------------
__global__ __launch_bounds__(256) void k_out(
    const float* __restrict__ x, const float* __restrict__ upd,
    const float* __restrict__ w_f, const float* __restrict__ g_f,
    const float* __restrict__ be_f, const float* __restrict__ rm_f,
    const float* __restrict__ rv_f, float* __restrict__ out)
{
    const int b  = blockIdx.z;
    const int vt = blockIdx.x * 64;
    const int ot = blockIdx.y * 64;
    const int tid = threadIdx.x;
    const int tx = tid & 15, ty = tid >> 4;
    const float* xb = x + (size_t)b * C * V;
    const float* ub = upd + (size_t)b * C2 * V;

    __shared__ float Wt[16][68];
    __shared__ float Bt[16][64];

    float acc[4][4] = {};

    for (int k0 = 0; k0 < C + C2; k0 += 16) {
        const float* src = (k0 < C) ? xb : ub;
        const int row = (k0 < C) ? k0 : (k0 - C);
        #pragma unroll
        for (int r = 0; r < 4; ++r) {
            int o = (tid >> 4) + r * 16;
            int c = tid & 15;
            Wt[c][o] = w_f[(size_t)(ot + o) * (C + C2) + k0 + c];
        }
        #pragma unroll
        for (int r = 0; r < 4; ++r) {
            int c = (tid >> 6) + r * 4;
            int vv = tid & 63;
            Bt[c][vv] = src[(size_t)(row + c) * V + vt + vv];
        }
        __syncthreads();
        #pragma unroll
        for (int c = 0; c < 16; ++c) {
            const float4 wv = *(const float4*)(&Wt[c][ty * 4]);
            const float4 bv = *(const float4*)(&Bt[c][tx * 4]);
            const float wa[4] = {wv.x, wv.y, wv.z, wv.w};
            const float ba[4] = {bv.x, bv.y, bv.z, bv.w};
            #pragma unroll
            for (int oi = 0; oi < 4; ++oi)
                #pragma unroll
                for (int vi = 0; vi < 4; ++vi)
                    acc[oi][vi] = fmaf(wa[oi], ba[vi], acc[oi][vi]);
        }
        __syncthreads();
    }

    #pragma unroll
    for (int oi = 0; oi < 4; ++oi) {
        int o = ot + ty * 4 + oi;
        float sc  = rsqrtf(rv_f[o] + EPS) * g_f[o];
        float4 outv;
        float t;
        t = (acc[oi][0] - rm_f[o]) * sc + be_f[o]; outv.x = leaky(t);
        t = (acc[oi][1] - rm_f[o]) * sc + be_f[o]; outv.y = leaky(t);
        t = (acc[oi][2] - rm_f[o]) * sc + be_f[o]; outv.z = leaky(t);
        t = (acc[oi][3] - rm_f[o]) * sc + be_f[o]; outv.w = leaky(t);
        *(float4*)(&out[((size_t)b * C + o) * V + vt + tx * 4]) = outv;
    }
}

// ---------------------------------------------------------------------------
extern "C" void kernel_launch(void* const* d_in, const int* in_sizes, int n_in,
                              void* d_out, int out_size, void* d_ws, size_t ws_size,
                              hipStream_t stream)
{
    const float* x    = (const float*)d_in[0];
    const float* topo = (const float*)d_in[1];
    const float* w_ea = (const float*)d_in[2];
    const float* b_ea = (const float*)d_in[3];
    const float* g_ea = (const float*)d_in[4];
    const float* be_ea= (const float*)d_in[5];
    const float* rm_ea= (const float*)d_in[6];
    const float* rv_ea= (const float*)d_in[7];
    const float* w_v  = (const float*)d_in[8];
    const float* b_v  = (const float*)d_in[9];
    const float* g_v  = (const float*)d_in[10];
    const float* be_v = (const float*)d_in[11];
    const float* rm_v = (const float*)d_in[12];
    const float* rv_v = (const float*)d_in[13];
    const float* w_e  = (const float*)d_in[14];
    const float* b_e  = (const float*)d_in[15];
    const float* g_e  = (const float*)d_in[16];
    const float* be_e = (const float*)d_in[17];
    const float* rm_e = (const float*)d_in[18];
    const float* rv_e = (const float*)d_in[19];
    const float* w_r  = (const float*)d_in[20];
    const float* b_r  = (const float*)d_in[21];
    const float* g_r  = (const float*)d_in[22];
    const float* be_r = (const float*)d_in[23];
    const float* rm_r = (const float*)d_in[24];
    const float* rv_r = (const float*)d_in[25];
    const float* w_f  = (const float*)d_in[26];
    const float* g_f  = (const float*)d_in[27];
    const float* be_f = (const float*)d_in[28];
    const float* rm_f = (const float*)d_in[29];
    const float* rv_f = (const float*)d_in[30];

    float* ws   = (float*)d_ws;
    float* agg  = ws;                                   // BATCH*C*V   = 4,194,304 f
    float* uvb  = ws + (size_t)BATCH * C * V;           // BATCH*C2*V  = 2,097,152 f
    float* updb = uvb + (size_t)BATCH * C2 * V;         // BATCH*C2*V  = 2,097,152 f
    float* out  = (float*)d_out;

    // A: agg
    k_agg<<<dim3((BATCH * C * V) / 256), 256, 0, stream>>>(
        x, topo, w_ea, b_ea, g_ea, be_ea, rm_ea, rv_ea, agg);
    // B: uv
    k_uv<<<dim3(V / 64, C2 / 64, BATCH), 256, 0, stream>>>(
        x, agg, w_v, b_v, g_v, be_v, rm_v, rv_v, uvb);
    // C: upd
    k_upd<<<dim3(V / 64, C2 / 64, BATCH), 256, 0, stream>>>(
        x, topo, w_e, b_e, g_e, be_e, rm_e, rv_e,
        w_r, b_r, g_r, be_r, rm_r, rv_r, uvb, updb);
    // D: out
    k_out<<<dim3(V / 64, C / 64, BATCH), 256, 0, stream>>>(
        x, updb, w_f, g_f, be_f, rm_f, rv_f, out);
}

// Round 2
// 164.937 us; speedup vs baseline: 3.4632x; 3.4632x over previous
//
#include <hip/hip_runtime.h>

#define BATCH 2
#define C 512
#define C2 256
#define V 4096          // 16*16*16
#define NROWS 8192      // BATCH*V
#define EPS 1e-5f
#define SLOPE 0.01f

typedef __bf16 bf16;
typedef __bf16 bf16x8 __attribute__((ext_vector_type(8)));
typedef __bf16 bf16x4 __attribute__((ext_vector_type(4)));
typedef float  f32x4  __attribute__((ext_vector_type(4)));

__device__ __forceinline__ float leaky(float x) { return x >= 0.f ? x : SLOPE * x; }

// neighbor voxel (within batch) for shift k: 0:d-1 1:d+1 2:w-1 3:w+1 4:h-1 5:h+1 (cyclic)
__device__ __forceinline__ int nbr(int v, int k) {
    int h = v & 15, w = (v >> 4) & 15, d = v >> 8;
    switch (k) {
        case 0: return (v & 0x0FF) | (((d + 15) & 15) << 8);
        case 1: return (v & 0x0FF) | (((d + 1) & 15) << 8);
        case 2: return (v & 0xF0F) | (((w + 15) & 15) << 4);
        case 3: return (v & 0xF0F) | (((w + 1) & 15) << 4);
        case 4: return (v & 0xFF0) | ((h + 15) & 15);
        default: return (v & 0xFF0) | ((h + 1) & 15);
    }
}

// ---------------------------------------------------------------------------
// prep: fold BN into scalar params + per-channel biases
// P[0..5]=w_ea', P[6]=b_ea', P[8..13]=w_r', P[14]=b_r'
// ---------------------------------------------------------------------------
__global__ __launch_bounds__(512) void k_prep_scal(
    const float* w_ea, const float* b_ea, const float* g_ea, const float* be_ea,
    const float* rm_ea, const float* rv_ea,
    const float* b_v, const float* g_v, const float* be_v, const float* rm_v, const float* rv_v,
    const float* b_e, const float* g_e, const float* be_e, const float* rm_e, const float* rv_e,
    const float* w_r, const float* b_r, const float* g_r, const float* be_r,
    const float* rm_r, const float* rv_r,
    const float* g_f, const float* be_f, const float* rm_f, const float* rv_f,
    float* P, float* obv, float* obe, float* obf)
{
    int t = threadIdx.x;
    if (t < 512) obf[t] = be_f[t] - rsqrtf(rv_f[t] + EPS) * g_f[t] * rm_f[t];
    if (t < 256) {
        float sv = rsqrtf(rv_v[t] + EPS) * g_v[t];
        obv[t] = sv * (b_v[t] - rm_v[t]) + be_v[t];
        float se = rsqrtf(rv_e[t] + EPS) * g_e[t];
        obe[t] = se * (b_e[t] - rm_e[t]) + be_e[t];
    }
    if (t < 6) {
        float sa = rsqrtf(rv_ea[0] + EPS) * g_ea[0];
        P[t] = sa * w_ea[t];
        float sr = rsqrtf(rv_r[0] + EPS) * g_r[0];
        P[8 + t] = sr * w_r[t];
    }
    if (t == 6) {
        float sa = rsqrtf(rv_ea[0] + EPS) * g_ea[0];
        P[6] = sa * (b_ea[0] - rm_ea[0]) + be_ea[0];
        float sr = rsqrtf(rv_r[0] + EPS) * g_r[0];
        P[14] = sr * (b_r[0] - rm_r[0]) + be_r[0];
    }
}

// ---------------------------------------------------------------------------
// prep: fold BN scale into weights, convert to bf16
// wv 256x1024 | we 256x1024 | wf 512x768
// ---------------------------------------------------------------------------
__global__ __launch_bounds__(256) void k_prep_w(
    const float* wv, const float* gv, const float* rvv,
    const float* we, const float* ge, const float* rve,
    const float* wf, const float* gf, const float* rvf,
    bf16* owv, bf16* owe, bf16* owf)
{
    int i = blockIdx.x * 256 + threadIdx.x;
    if (i < 262144) {
        int o = i >> 10;
        owv[i] = (bf16)(rsqrtf(rvv[o] + EPS) * gv[o] * wv[i]);
    } else if (i < 524288) {
        int j = i - 262144; int o = j >> 10;
        owe[j] = (bf16)(rsqrtf(rve[o] + EPS) * ge[o] * we[j]);
    } else if (i < 917504) {
        int j = i - 524288; int o = j / 768;
        owf[j] = (bf16)(rsqrtf(rvf[o] + EPS) * gf[o] * wf[j]);
    }
}

// ---------------------------------------------------------------------------
// k_aggT: per (b, 64c x 64v) tile: compute agg + (optionally) 6 edge features,
// write xT/aggT/edgeT transposed to [b*V+v][c] bf16 via LDS.
// ---------------------------------------------------------------------------
template<bool EMAT>
__global__ __launch_bounds__(256) void k_aggT(
    const float* __restrict__ x, const float* __restrict__ topo,
    const float* __restrict__ P,
    bf16* __restrict__ xT, bf16* __restrict__ aggT, bf16* __restrict__ edgeT)
{
    __shared__ float T[64][65];
    const int t = threadIdx.x;
    const int b = blockIdx.z, ct = blockIdx.y * 64, vt = blockIdx.x * 64;
    const int cl = t >> 2;              // local c row 0..63
    const int c  = ct + cl;
    const int vl0 = (t & 3) * 16;       // local v start (16-aligned h-row)
    const int v0 = vt + vl0;
    const int w = (v0 >> 4) & 15, d = v0 >> 8;
    const float* xp = x + (((size_t)b * C + c) << 12);

    float xr[16], xd0[16], xd1[16], xw0[16], xw1[16];
    #pragma unroll
    for (int i = 0; i < 4; i++) {
        float4 a;
        a = ((const float4*)(xp + v0))[i];                             xr [4*i]=a.x; xr [4*i+1]=a.y; xr [4*i+2]=a.z; xr [4*i+3]=a.w;
        a = ((const float4*)(xp + (((d+15)&15)<<8) + (w<<4)))[i];      xd0[4*i]=a.x; xd0[4*i+1]=a.y; xd0[4*i+2]=a.z; xd0[4*i+3]=a.w;
        a = ((const float4*)(xp + (((d+ 1)&15)<<8) + (w<<4)))[i];      xd1[4*i]=a.x; xd1[4*i+1]=a.y; xd1[4*i+2]=a.z; xd1[4*i+3]=a.w;
        a = ((const float4*)(xp + (d<<8) + (((w+15)&15)<<4)))[i];      xw0[4*i]=a.x; xw0[4*i+1]=a.y; xw0[4*i+2]=a.z; xw0[4*i+3]=a.w;
        a = ((const float4*)(xp + (d<<8) + (((w+ 1)&15)<<4)))[i];      xw1[4*i]=a.x; xw1[4*i+1]=a.y; xw1[4*i+2]=a.z; xw1[4*i+3]=a.w;
    }

    const int NPASS = EMAT ? 8 : 2;
    #pragma unroll
    for (int p = 0; p < 8; ++p) {
        if (p >= NPASS) break;
        float val[16];
        if (p == 0) {
            #pragma unroll
            for (int j = 0; j < 16; j++) val[j] = xr[j];
        } else if (p == 1) {
            #pragma unroll
            for (int j = 0; j < 16; j++) {
                const float* tp = topo + (size_t)(v0 + j) * 6;
                float s = P[6];
                s = fmaf(P[0], fmaf(xd0[j], xr[j], tp[0]), s);
                s = fmaf(P[1], fmaf(xd1[j], xr[j], tp[1]), s);
                s = fmaf(P[2], fmaf(xw0[j], xr[j], tp[2]), s);
                s = fmaf(P[3], fmaf(xw1[j], xr[j], tp[3]), s);
                s = fmaf(P[4], fmaf(xr[(j+15)&15], xr[j], tp[4]), s);
                s = fmaf(P[5], fmaf(xr[(j+ 1)&15], xr[j], tp[5]), s);
                val[j] = leaky(s);
            }
        } else {
            const int k = p - 2;
            #pragma unroll
            for (int j = 0; j < 16; j++) {
                float xn = (k==0) ? xd0[j] : (k==1) ? xd1[j] : (k==2) ? xw0[j]
                         : (k==3) ? xw1[j] : (k==4) ? xr[(j+15)&15] : xr[(j+1)&15];
                val[j] = fmaf(xn, xr[j], topo[(size_t)(v0 + j) * 6 + k]);
            }
        }
        __syncthreads();
        #pragma unroll
        for (int j = 0; j < 16; j++) T[cl][vl0 + j] = val[j];
        __syncthreads();
        // transposed write: thread -> one v row, 16 c's
        const int vr = t >> 2, c0 = (t & 3) * 16;
        bf16x8 lo, hi;
        #pragma unroll
        for (int i = 0; i < 8; i++) {
            lo[i] = (bf16)T[c0 + i][vr];
            hi[i] = (bf16)T[c0 + 8 + i][vr];
        }
        bf16* dst = (p == 0) ? xT : (p == 1) ? aggT
                  : edgeT + (size_t)(p - 2) * ((size_t)NROWS * C);
        bf16* dp = dst + ((size_t)(b << 12) + vt + vr) * C + ct + c0;
        *(bf16x8*)dp = lo;
        *(bf16x8*)(dp + 8) = hi;
    }
}

// ---------------------------------------------------------------------------
// GEMM helpers: 128x128 tile, BK=32, 8 waves (2m x 4n), wave tile 64x32.
// LDS rows padded to 40 bf16 (80B) -> 2-way banks (free).
// ---------------------------------------------------------------------------
__device__ __forceinline__ void stage16(bf16* lds, const bf16* src, size_t ld,
                                        int rowBase, int col, int t)
{
    const int row = t >> 2, slot = t & 3;
    *(uint4*)(lds + row * 40 + slot * 8) =
        *(const uint4*)(src + (size_t)(rowBase + row) * ld + col + slot * 8);
}

__device__ __forceinline__ void mm8(const bf16* Alds, const bf16* Blds,
                                    f32x4 acc[4][2], int arow, int brow, int kg)
{
    bf16x8 af[4], bfr[2];
    #pragma unroll
    for (int mb = 0; mb < 4; mb++)
        af[mb] = *(const bf16x8*)(Alds + (arow + mb * 16) * 40 + kg * 8);
    #pragma unroll
    for (int nb = 0; nb < 2; nb++)
        bfr[nb] = *(const bf16x8*)(Blds + (brow + nb * 16) * 40 + kg * 8);
    #pragma unroll
    for (int mb = 0; mb < 4; mb++)
        #pragma unroll
        for (int nb = 0; nb < 2; nb++)
            acc[mb][nb] = __builtin_amdgcn_mfma_f32_16x16x32_bf16(af[mb], bfr[nb], acc[mb][nb], 0, 0, 0);
}

// ---------------------------------------------------------------------------
// k_upd: fused uv-GEMM + sxe + 6 edge phases + reductions.  M=256, N=8192.
//   uv  = leaky(Wv'.[xT;aggT] + bv')          (kept in registers)
//   sxe = We'[:, :512].xT
//   per k: ue_k = leaky(sxe + We'[:,512:].edge_k + be'); ur += wr'[k]*ue_k
//   updT = uv * leaky(ur + br')               (bf16, [row][o] layout)
// ---------------------------------------------------------------------------
template<bool EMAT>
__global__ __launch_bounds__(512, 2) void k_upd(
    const bf16* __restrict__ xT, const bf16* __restrict__ aggT,
    const bf16* __restrict__ edgeT,
    const bf16* __restrict__ wv, const bf16* __restrict__ we,
    const float* __restrict__ bv, const float* __restrict__ be,
    const float* __restrict__ P, const float* __restrict__ topo,
    bf16* __restrict__ updT)
{
    __shared__ __align__(16) bf16 Alds[128 * 40];
    __shared__ __align__(16) bf16 Blds[128 * 40];
    const int t = threadIdx.x;
    const int lane = t & 63, wid = t >> 6;
    const int wm = wid >> 2, wn = wid & 3;
    const int lr = lane & 15, kg = lane >> 4;
    const int n0 = blockIdx.x * 128;
    const int m0 = blockIdx.y * 128;
    const int arow = wm * 64 + lr;
    const int brow = wn * 32 + lr;

    f32x4 uvr[4][2], sxe[4][2], ur[4][2], cur[4][2];
    #pragma unroll
    for (int mb = 0; mb < 4; mb++)
        #pragma unroll
        for (int nb = 0; nb < 2; nb++) { uvr[mb][nb] = 0.f; sxe[mb][nb] = 0.f; ur[mb][nb] = 0.f; }

    // ---- phase uv: K=1024 over [xT ; aggT] ----
    #pragma unroll 1
    for (int kc = 0; kc < 32; ++kc) {
        __syncthreads();
        stage16(Alds, wv, 1024, m0, kc * 32, t);
        stage16(Blds, (kc < 16) ? xT : aggT, C, n0, (kc & 15) * 32, t);
        __syncthreads();
        mm8(Alds, Blds, uvr, arow, brow, kg);
    }
    {   // activate uv in registers
        f32x4 bvv[4];
        #pragma unroll
        for (int mb = 0; mb < 4; mb++)
            bvv[mb] = *(const f32x4*)(bv + m0 + wm * 64 + mb * 16 + kg * 4);
        #pragma unroll
        for (int mb = 0; mb < 4; mb++)
            #pragma unroll
            for (int nb = 0; nb < 2; nb++)
                #pragma unroll
                for (int q = 0; q < 4; q++)
                    uvr[mb][nb][q] = leaky(uvr[mb][nb][q] + bvv[mb][q]);
    }

    // ---- phase sxe: K=512 over xT with We[:, :512] ----
    #pragma unroll 1
    for (int kc = 0; kc < 16; ++kc) {
        __syncthreads();
        stage16(Alds, we, 1024, m0, kc * 32, t);
        stage16(Blds, xT, C, n0, kc * 32, t);
        __syncthreads();
        mm8(Alds, Blds, sxe, arow, brow, kg);
    }

    f32x4 bev[4];
    #pragma unroll
    for (int mb = 0; mb < 4; mb++)
        bev[mb] = *(const f32x4*)(be + m0 + wm * 64 + mb * 16 + kg * 4);

    // ---- 6 edge phases ----
    #pragma unroll 1
    for (int k = 0; k < 6; ++k) {
        #pragma unroll
        for (int mb = 0; mb < 4; mb++)
            #pragma unroll
            for (int nb = 0; nb < 2; nb++) cur[mb][nb] = sxe[mb][nb];
        #pragma unroll 1
        for (int kc = 0; kc < 16; ++kc) {
            __syncthreads();
            stage16(Alds, we, 1024, m0, 512 + kc * 32, t);
            if (EMAT) {
                stage16(Blds, edgeT + (size_t)k * ((size_t)NROWS * C), C, n0, kc * 32, t);
            } else {
                const int row = t >> 2, slot = t & 3;
                const int nrow = n0 + row, b = nrow >> 12, v = nrow & 4095;
                const int nbv = (b << 12) + nbr(v, k);
                bf16x8 xa = *(const bf16x8*)(xT + (size_t)nrow * C + kc * 32 + slot * 8);
                bf16x8 xn = *(const bf16x8*)(xT + (size_t)nbv * C + kc * 32 + slot * 8);
                const float tp = topo[(size_t)v * 6 + k];
                bf16x8 e;
                #pragma unroll
                for (int j = 0; j < 8; j++)
                    e[j] = (bf16)fmaf((float)xa[j], (float)xn[j], tp);
                *(bf16x8*)(Blds + row * 40 + slot * 8) = e;
            }
            __syncthreads();
            mm8(Alds, Blds, cur, arow, brow, kg);
        }
        const float wrk = P[8 + k];
        #pragma unroll
        for (int mb = 0; mb < 4; mb++)
            #pragma unroll
            for (int nb = 0; nb < 2; nb++)
                #pragma unroll
                for (int q = 0; q < 4; q++) {
                    float ue = leaky(cur[mb][nb][q] + bev[mb][q]);
                    ur[mb][nb][q] = fmaf(wrk, ue, ur[mb][nb][q]);
                }
    }

    // ---- epilogue: updT[row][o] = uv * leaky(ur + br') ----
    const float brp = P[14];
    #pragma unroll
    for (int mb = 0; mb < 4; mb++)
        #pragma unroll
        for (int nb = 0; nb < 2; nb++) {
            const int col = n0 + wn * 32 + nb * 16 + lr;          // (b,v) row
            const int o = m0 + wm * 64 + mb * 16 + kg * 4;        // 4 consecutive o
            bf16x4 o4;
            #pragma unroll
            for (int q = 0; q < 4; q++) {
                float u2 = leaky(ur[mb][nb][q] + brp);
                o4[q] = (bf16)(uvr[mb][nb][q] * u2);
            }
            *(bf16x4*)(updT + (size_t)col * C2 + o) = o4;
        }
}

// ---------------------------------------------------------------------------
// k_out: M=512, K=768 ([xT(512) ; updT(256)]), N=8192 -> d_out fp32 [b][o][v]
// ---------------------------------------------------------------------------
__global__ __launch_bounds__(512, 2) void k_out(
    const bf16* __restrict__ xT, const bf16* __restrict__ updT,
    const bf16* __restrict__ wf, const float* __restrict__ bf,
    float* __restrict__ out)
{
    __shared__ __align__(16) bf16 Alds[128 * 40];
    __shared__ __align__(16) bf16 Blds[128 * 40];
    const int t = threadIdx.x;
    const int lane = t & 63, wid = t >> 6;
    const int wm = wid >> 2, wn = wid & 3;
    const int lr = lane & 15, kg = lane >> 4;
    const int n0 = blockIdx.x * 128;
    const int m0 = blockIdx.y * 128;
    const int arow = wm * 64 + lr;
    const int brow = wn * 32 + lr;

    f32x4 acc[4][2];
    #pragma unroll
    for (int mb = 0; mb < 4; mb++)
        #pragma unroll
        for (int nb = 0; nb < 2; nb++) acc[mb][nb] = 0.f;

    #pragma unroll 1
    for (int kc = 0; kc < 24; ++kc) {
        __syncthreads();
        stage16(Alds, wf, 768, m0, kc * 32, t);
        if (kc < 16) stage16(Blds, xT, C, n0, kc * 32, t);
        else         stage16(Blds, updT, C2, n0, (kc - 16) * 32, t);
        __syncthreads();
        mm8(Alds, Blds, acc, arow, brow, kg);
    }

    f32x4 bfv[4];
    #pragma unroll
    for (int mb = 0; mb < 4; mb++)
        bfv[mb] = *(const f32x4*)(bf + m0 + wm * 64 + mb * 16 + kg * 4);

    #pragma unroll
    for (int mb = 0; mb < 4; mb++)
        #pragma unroll
        for (int nb = 0; nb < 2; nb++) {
            const int col = n0 + wn * 32 + nb * 16 + lr;
            const int b = col >> 12, v = col & 4095;
            const int o = m0 + wm * 64 + mb * 16 + kg * 4;
            #pragma unroll
            for (int q = 0; q < 4; q++)
                out[(((size_t)b * C + o + q) << 12) + v] = leaky(acc[mb][nb][q] + bfv[mb][q]);
        }
}

// ---------------------------------------------------------------------------
extern "C" void kernel_launch(void* const* d_in, const int* in_sizes, int n_in,
                              void* d_out, int out_size, void* d_ws, size_t ws_size,
                              hipStream_t stream)
{
    const float* x    = (const float*)d_in[0];
    const float* topo = (const float*)d_in[1];
    const float* w_ea = (const float*)d_in[2];
    const float* b_ea = (const float*)d_in[3];
    const float* g_ea = (const float*)d_in[4];
    const float* be_ea= (const float*)d_in[5];
    const float* rm_ea= (const float*)d_in[6];
    const float* rv_ea= (const float*)d_in[7];
    const float* w_v  = (const float*)d_in[8];
    const float* b_v  = (const float*)d_in[9];
    const float* g_v  = (const float*)d_in[10];
    const float* be_v = (const float*)d_in[11];
    const float* rm_v = (const float*)d_in[12];
    const float* rv_v = (const float*)d_in[13];
    const float* w_e  = (const float*)d_in[14];
    const float* b_e  = (const float*)d_in[15];
    const float* g_e  = (const float*)d_in[16];
    const float* be_e = (const float*)d_in[17];
    const float* rm_e = (const float*)d_in[18];
    const float* rv_e = (const float*)d_in[19];
    const float* w_r  = (const float*)d_in[20];
    const float* b_r  = (const float*)d_in[21];
    const float* g_r  = (const float*)d_in[22];
    const float* be_r = (const float*)d_in[23];
    const float* rm_r = (const float*)d_in[24];
    const float* rv_r = (const float*)d_in[25];
    const float* w_f  = (const float*)d_in[26];
    const float* g_f  = (const float*)d_in[27];
    const float* be_f = (const float*)d_in[28];
    const float* rm_f = (const float*)d_in[29];
    const float* rv_f = (const float*)d_in[30];

    // workspace layout (256B aligned)
    char* base = (char*)d_ws;
    size_t off = 0;
    auto take = [&](size_t bytes) { size_t r = off; off = (off + bytes + 255) & ~(size_t)255; return r; };
    float* P    = (float*)(base + take(64 * 4));
    float* bvp  = (float*)(base + take(256 * 4));
    float* bep  = (float*)(base + take(256 * 4));
    float* bfp  = (float*)(base + take(512 * 4));
    bf16*  wvp  = (bf16*)(base + take((size_t)262144 * 2));
    bf16*  wep  = (bf16*)(base + take((size_t)262144 * 2));
    bf16*  wfp  = (bf16*)(base + take((size_t)393216 * 2));
    bf16*  xT   = (bf16*)(base + take((size_t)NROWS * C * 2));
    bf16*  aggT = (bf16*)(base + take((size_t)NROWS * C * 2));
    bf16*  updT = (bf16*)(base + take((size_t)NROWS * C2 * 2));
    bf16*  edgeT= (bf16*)(base + off);
    const size_t need_full = off + (size_t)6 * NROWS * C * 2;
    const bool EM = ws_size >= need_full;

    k_prep_scal<<<1, 512, 0, stream>>>(
        w_ea, b_ea, g_ea, be_ea, rm_ea, rv_ea,
        b_v, g_v, be_v, rm_v, rv_v,
        b_e, g_e, be_e, rm_e, rv_e,
        w_r, b_r, g_r, be_r, rm_r, rv_r,
        g_f, be_f, rm_f, rv_f,
        P, bvp, bep, bfp);
    k_prep_w<<<3584, 256, 0, stream>>>(
        w_v, g_v, rv_v, w_e, g_e, rv_e, w_f, g_f, rv_f, wvp, wep, wfp);

    dim3 gAgg(64, 8, 2);
    if (EM) k_aggT<true ><<<gAgg, 256, 0, stream>>>(x, topo, P, xT, aggT, edgeT);
    else    k_aggT<false><<<gAgg, 256, 0, stream>>>(x, topo, P, xT, aggT, edgeT);

    dim3 gUpd(64, 2);
    if (EM) k_upd<true ><<<gUpd, 512, 0, stream>>>(xT, aggT, edgeT, wvp, wep, bvp, bep, P, topo, updT);
    else    k_upd<false><<<gUpd, 512, 0, stream>>>(xT, aggT, edgeT, wvp, wep, bvp, bep, P, topo, updT);

    k_out<<<dim3(64, 4), 512, 0, stream>>>(xT, updT, wfp, bfp, (float*)d_out);
}